// Round 2
// baseline (76.292 us; speedup 1.0000x reference)
//
#include <hip/hip_runtime.h>

#define BATCH 512
#define KBITS 14
#define TABLE 16384

// Transpose [B][C] int32 (0/1) -> [C][B] bytes. idx = b*C + c: coalesced reads.
__global__ void transpose_pack(const int* __restrict__ in,
                               unsigned char* __restrict__ out,
                               int C) {
    int idx = blockIdx.x * blockDim.x + threadIdx.x;
    if (idx >= BATCH * C) return;
    int b = idx / C;
    int c = idx - b * C;
    out[(size_t)c * BATCH + b] = (unsigned char)(in[idx] & 1);
}

// One block = one neuron, 128 threads x 4 batch elements each.
// Input rows are transposed bit-bytes: row c = bit position c for all 512 batch elems.
__global__ __launch_bounds__(128)
void ram_layer(const unsigned char* __restrict__ in0,  // rows for c <  split
               const unsigned char* __restrict__ in1,  // rows for c >= split (indexed c-split)
               int split,
               const int* __restrict__ conn,           // [N][14]
               const int* __restrict__ mem,            // [N][16384] int32 0/1
               unsigned char* __restrict__ outT)       // [N][512] bytes
{
    const int n = blockIdx.x;
    const int b0 = threadIdx.x * 4;

    const int* cp = conn + n * KBITS;   // wave-uniform -> scalar loads

    unsigned int a0 = 0, a1 = 0, a2 = 0, a3 = 0;
#pragma unroll
    for (int k = 0; k < KBITS; ++k) {
        int c = cp[k];
        const unsigned char* row = (c < split) ? (in0 + (size_t)c * BATCH)
                                               : (in1 + (size_t)(c - split) * BATCH);
        unsigned int w = *(const unsigned int*)(row + b0);  // 4 batch elems' bits
        a0 += ((w      ) & 1u) << k;
        a1 += ((w >>  8) & 1u) << k;
        a2 += ((w >> 16) & 1u) << k;
        a3 += ((w >> 24) & 1u) << k;
    }

    const int* m = mem + (size_t)n * TABLE;
    uchar4 r;
    r.x = (unsigned char)(m[a0] & 1);
    r.y = (unsigned char)(m[a1] & 1);
    r.z = (unsigned char)(m[a2] & 1);
    r.w = (unsigned char)(m[a3] & 1);
    *(uchar4*)(outT + (size_t)n * BATCH + b0) = r;
}

// Convert transposed byte output [N][512] to int32 [B][N] (harness maps bool -> int32).
__global__ void out_convert(const unsigned char* __restrict__ oT,
                            int* __restrict__ out, int N) {
    int idx = blockIdx.x * blockDim.x + threadIdx.x;  // idx = b*N + n
    if (idx >= BATCH * N) return;
    int b = idx / N;
    int n = idx - b * N;
    out[idx] = (int)(oT[(size_t)n * BATCH + b] & 1);
}

extern "C" void kernel_launch(void* const* d_in, const int* in_sizes, int n_in,
                              void* d_out, int out_size, void* d_ws, size_t ws_size,
                              hipStream_t stream) {
    const int* x        = (const int*)d_in[0];  // [512][1024] int32 0/1
    const int* state    = (const int*)d_in[1];  // [512][2048] int32 0/1
    const int* in_conn  = (const int*)d_in[2];  // [4096][14]
    const int* st_conn  = (const int*)d_in[3];  // [2048][14]
    const int* out_conn = (const int*)d_in[4];  // [2048][14]
    const int* in_mem   = (const int*)d_in[5];  // [4096][16384] int32 0/1
    const int* st_mem   = (const int*)d_in[6];  // [2048][16384]
    const int* out_mem  = (const int*)d_in[7];  // [2048][16384]
    int* out = (int*)d_out;

    unsigned char* ws  = (unsigned char*)d_ws;
    unsigned char* xT  = ws;                               // 1024*512 = 512 KiB
    unsigned char* hsT = ws + 524288;                      // 6144*512 = 3 MiB (rows 0..4095 = h, 4096..6143 = state)
    unsigned char* sT  = ws + 524288 + 3145728;            // 2048*512 = 1 MiB
    unsigned char* oT  = ws + 524288 + 3145728 + 1048576;  // 2048*512 = 1 MiB

    // Transpose + pack inputs to [pos][batch] byte layout.
    transpose_pack<<<(512 * 1024) / 256, 256, 0, stream>>>(x, xT, 1024);
    transpose_pack<<<(512 * 2048) / 256, 256, 0, stream>>>(state, hsT + (size_t)4096 * 512, 2048);

    // Layer 1: h = in_mem lookup on x. Writes hsT rows 0..4095.
    ram_layer<<<4096, 128, 0, stream>>>(xT, xT, 1 << 30, in_conn, in_mem, hsT);
    // Layer 2: s = st_mem lookup on cat(h, state) = hsT rows 0..6143.
    ram_layer<<<2048, 128, 0, stream>>>(hsT, hsT, 1 << 30, st_conn, st_mem, sT);
    // Layer 3: out = out_mem lookup on cat(h, s): rows <4096 from hsT, >=4096 from sT[c-4096].
    ram_layer<<<2048, 128, 0, stream>>>(hsT, sT, 4096, out_conn, out_mem, oT);

    // Convert to int32 [B][N_OUT].
    out_convert<<<(BATCH * 2048) / 256, 256, 0, stream>>>(oT, out, 2048);
}

// Round 3
// 66.506 us; speedup vs baseline: 1.1471x; 1.1471x over previous
//
#include <hip/hip_runtime.h>

#define BATCH 512
#define KBITS 14
#define TABLE 16384

// ---------------------------------------------------------------------------
// Layout: activation rows are bit-packed transposed: row r = 64 bytes,
// byte t holds batches t*8 .. t*8+7 (bit j = batch t*8+j).
// ---------------------------------------------------------------------------

// Tiled transpose + bit-pack: in = [512][C] int32 0/1, out rows = packed [C][64].
// Block handles a 64-batch x 64-col tile. Coalesced global reads, LDS transpose.
__global__ __launch_bounds__(256)
void tp_pack(const int* __restrict__ in, unsigned char* __restrict__ out, int C) {
    __shared__ unsigned char lds[64 * 65];
    const int c0 = blockIdx.x * 64;
    const int b0 = blockIdx.y * 64;
    const int t = threadIdx.x;

#pragma unroll
    for (int i = 0; i < 16; ++i) {
        int flat = i * 256 + t;          // 0..4095
        int brow = flat >> 6;            // batch offset 0..63
        int ccol = flat & 63;            // col offset 0..63
        lds[ccol * 65 + brow] = (unsigned char)(in[(size_t)(b0 + brow) * C + (c0 + ccol)] & 1);
    }
    __syncthreads();

    const int c = t >> 2;                // 0..63
    const int q = t & 3;                 // 0..3 -> bytes 2q, 2q+1
#pragma unroll
    for (int jj = 0; jj < 2; ++jj) {
        int j = q * 2 + jj;              // byte index 0..7 within this tile's 8 bytes
        unsigned int byte = 0;
#pragma unroll
        for (int i = 0; i < 8; ++i)
            byte |= ((unsigned int)lds[c * 65 + j * 8 + i] & 1u) << i;
        out[(size_t)(c0 + c) * 64 + (b0 >> 3) + j] = (unsigned char)byte;
    }
}

// One wave (64 lanes) = one neuron; lane t handles batches t*8 .. t*8+7.
// Each gather is one 64-byte line per wave; 8 independent table loads in flight.
__global__ __launch_bounds__(128)
void ram_layer_p(const unsigned char* __restrict__ in0,  // packed rows, c < split
                 const unsigned char* __restrict__ in1,  // packed rows, c >= split (index c-split)
                 int split,
                 const int* __restrict__ conn,           // [N][14]
                 const int* __restrict__ mem,            // [N][16384] int32 0/1
                 unsigned char* __restrict__ outP)       // [N][64] packed
{
    const int n = blockIdx.x * 2 + (threadIdx.x >> 6);
    const int t = threadIdx.x & 63;
    const int* cp = conn + n * KBITS;

    unsigned char w[KBITS];
#pragma unroll
    for (int k = 0; k < KBITS; ++k) {
        int c = cp[k];
        const unsigned char* row = (c < split) ? (in0 + (size_t)c * 64)
                                               : (in1 + (size_t)(c - split) * 64);
        w[k] = row[t];                   // wave reads 64 consecutive bytes = 1 line
    }

    unsigned int a[8] = {0, 0, 0, 0, 0, 0, 0, 0};
#pragma unroll
    for (int k = 0; k < KBITS; ++k) {
#pragma unroll
        for (int j = 0; j < 8; ++j)
            a[j] |= (((unsigned int)w[k] >> j) & 1u) << k;
    }

    const int* m = mem + (size_t)n * TABLE;
    int r[8];
#pragma unroll
    for (int j = 0; j < 8; ++j) r[j] = m[a[j]];   // 8 independent random loads
    unsigned int res = 0;
#pragma unroll
    for (int j = 0; j < 8; ++j) res |= ((unsigned int)r[j] & 1u) << j;

    outP[(size_t)n * 64 + t] = (unsigned char)res;  // wave writes 64 contiguous bytes
}

// Unpack [N=2048][64] packed output to int32 [512][2048]. Coalesced stores;
// reads hit a 128 KB L1/L2-resident buffer.
__global__ __launch_bounds__(256)
void out_convert_p(const unsigned char* __restrict__ oP, int* __restrict__ out) {
    int idx = blockIdx.x * blockDim.x + threadIdx.x;  // b*2048 + n
    int b = idx >> 11;
    int n = idx & 2047;
    out[idx] = (oP[(size_t)n * 64 + (b >> 3)] >> (b & 7)) & 1;
}

extern "C" void kernel_launch(void* const* d_in, const int* in_sizes, int n_in,
                              void* d_out, int out_size, void* d_ws, size_t ws_size,
                              hipStream_t stream) {
    const int* x        = (const int*)d_in[0];  // [512][1024] int32 0/1
    const int* state    = (const int*)d_in[1];  // [512][2048] int32 0/1
    const int* in_conn  = (const int*)d_in[2];  // [4096][14]
    const int* st_conn  = (const int*)d_in[3];  // [2048][14]
    const int* out_conn = (const int*)d_in[4];  // [2048][14]
    const int* in_mem   = (const int*)d_in[5];  // [4096][16384]
    const int* st_mem   = (const int*)d_in[6];  // [2048][16384]
    const int* out_mem  = (const int*)d_in[7];  // [2048][16384]
    int* out = (int*)d_out;

    unsigned char* ws  = (unsigned char*)d_ws;
    unsigned char* xP  = ws;                    // [1024][64] =  64 KiB
    unsigned char* hsP = ws + (64 << 10);       // [6144][64] = 384 KiB (rows 0..4095 = h, 4096..6143 = state)
    unsigned char* sP  = ws + (448 << 10);      // [2048][64] = 128 KiB
    unsigned char* oP  = ws + (576 << 10);      // [2048][64] = 128 KiB

    // Transpose + bit-pack inputs.
    dim3 gx(1024 / 64, 512 / 64);
    tp_pack<<<gx, 256, 0, stream>>>(x, xP, 1024);
    dim3 gs(2048 / 64, 512 / 64);
    tp_pack<<<gs, 256, 0, stream>>>(state, hsP + (size_t)4096 * 64, 2048);

    // Layer 1: h = in_mem[x-addr]; writes hsP rows 0..4095.
    ram_layer_p<<<4096 / 2, 128, 0, stream>>>(xP, xP, 1 << 30, in_conn, in_mem, hsP);
    // Layer 2: s = st_mem[cat(h,state)-addr]; all 6144 rows live in hsP.
    ram_layer_p<<<2048 / 2, 128, 0, stream>>>(hsP, hsP, 1 << 30, st_conn, st_mem, sP);
    // Layer 3: out = out_mem[cat(h,s)-addr]; c<4096 -> hsP, c>=4096 -> sP[c-4096].
    ram_layer_p<<<2048 / 2, 128, 0, stream>>>(hsP, sP, 4096, out_conn, out_mem, oP);

    // Unpack to int32 [512][2048].
    out_convert_p<<<(BATCH * 2048) / 256, 256, 0, stream>>>(oP, out);
}